// Round 4
// baseline (3935.064 us; speedup 1.0000x reference)
//
#include <hip/hip_runtime.h>
#include <math.h>

constexpr int WID  = 320;
constexpr int HWc  = 320 * 320;        // 102400
constexpr int NIMG = 16;
constexpr int NSL  = 32;               // B*C slices for TV/DWT
constexpr int NTOT = NIMG * 2 * HWc;   // 3276800 floats per full array
constexpr float LAM_TV  = 0.005f;
constexpr float LAM_WAV = 0.005f;

// R16 = R15 (persistent mega-kernel) + barrier INIT FIX. R15 hung: the
// harness POISONS the workspace before every run (fillBufferAligned, 256MiB
// pattern writes visible in rocprof), so bar.cnt started non-zero and the
// sense-reversing barrier could never fire. build_tw (same stream, runs
// before mega, graph-capture-safe, idempotent across replays) now zeroes the
// barrier words. Phase bodies remain verbatim R12 math.

__device__ __forceinline__ float softt(float v) {
    float a = fmaxf(fabsf(v) - LAM_WAV, 0.f);
    return copysignf(a, v);
}

__device__ __forceinline__ float fast_rsq(float x) {
    float r;
    asm volatile("v_rsq_f32 %0, %1" : "=v"(r) : "v"(x));
    return r;
}

// ================= 320-point FFT core ======================================
// 320 = 5 (register DFT) x 64 (lane FFT via shfl_xor). Centered transform via
// (-1)^n modulation at load and (-1)^k at store (handled by callers).
struct Tw { float tc, ts; float stc[6], sts[6]; };

__global__ void build_tw(float* tb, unsigned* bar) {
    const int lane = threadIdx.x;   // 64 threads
    if (lane < 2) bar[lane] = 0u;   // REQUIRED: ws is poisoned by harness
#pragma unroll
    for (int g = 0; g < 2; g++) {
        const float sgn = g ? 1.f : -1.f;
        float* p = tb + g * 14 * 64;
        float ts, tc;
        __sincosf(sgn * 6.283185307179586f * (float)lane / 320.f, &ts, &tc);
        p[lane] = tc; p[64 + lane] = ts;
#pragma unroll
        for (int s = 0; s < 6; s++) {
            int h = 32 >> s;
            int j = lane & (h - 1);
            float ang = sgn * 3.14159265358979323f * (float)j / (float)h;
            float ss, cc;
            __sincosf(ang, &ss, &cc);
            p[(2 + s) * 64 + lane] = cc;
            p[(8 + s) * 64 + lane] = ss;
        }
    }
}

__device__ __forceinline__ Tw load_tw(const float* __restrict__ tb, int lane) {
    Tw tw;
    tw.tc = tb[lane];
    tw.ts = tb[64 + lane];
#pragma unroll
    for (int s = 0; s < 6; s++) {
        tw.stc[s] = tb[(2 + s) * 64 + lane];
        tw.sts[s] = tb[(8 + s) * 64 + lane];
    }
    return tw;
}

template<int SGN>
__device__ __forceinline__ void fft320_core(const float (&vr)[5], const float (&vi)[5],
                                            float (&Cr)[5], float (&Ci)[5],
                                            const Tw& tw, int lane) {
    const float cw1 = 0.30901699437494745f, sw1 = 0.9510565162951535f;
    const float cw2 = -0.8090169943749475f, sw2 = 0.5877852522924731f;
    const float cwt[5] = {1.f, cw1, cw2, cw2, cw1};
    const float swt[5] = {0.f, sw1, sw2, -sw2, -sw1};
    Cr[0] = vr[0] + vr[1] + vr[2] + vr[3] + vr[4];
    Ci[0] = vi[0] + vi[1] + vi[2] + vi[3] + vi[4];
#pragma unroll
    for (int k = 1; k < 5; k++) {
        float ar = vr[0], ai = vi[0];
#pragma unroll
        for (int m = 1; m < 5; m++) {
            int j = (m * k) % 5;
            float wr_ = cwt[j], wi_ = (float)SGN * swt[j];
            ar += vr[m] * wr_ - vi[m] * wi_;
            ai += vr[m] * wi_ + vi[m] * wr_;
        }
        Cr[k] = ar; Ci[k] = ai;
    }
    float twr = 1.f, twi = 0.f;
#pragma unroll
    for (int k = 1; k < 5; k++) {
        float nr = twr * tw.tc - twi * tw.ts;
        twi = twr * tw.ts + twi * tw.tc;
        twr = nr;
        float r = Cr[k] * twr - Ci[k] * twi;
        Ci[k]   = Cr[k] * twi + Ci[k] * twr;
        Cr[k]   = r;
    }
#pragma unroll
    for (int s = 0; s < 6; s++) {
        int h = 32 >> s;
        bool up = (lane & h) != 0;
#pragma unroll
        for (int k = 0; k < 5; k++) {
            float orr = __shfl_xor(Cr[k], h);
            float oii = __shfl_xor(Ci[k], h);
            if (up) {
                float dr = orr - Cr[k], di = oii - Ci[k];
                Cr[k] = dr * tw.stc[s] - di * tw.sts[s];
                Ci[k] = dr * tw.sts[s] + di * tw.stc[s];
            } else {
                Cr[k] += orr;
                Ci[k] += oii;
            }
        }
    }
}

// ---------------- row FFT phase (grid-stride over 5120 lines) ---------------
// EPI: 0 = plain store; 2 = residual (out = aux1 - val, aux1 prefetched);
//      3 = dual store (out and out2).
constexpr int NLINES = NIMG * 320;     // 5120

template<int SGN, int EPI>
__device__ void row_phase(const float* __restrict__ in, float* __restrict__ out,
                          const float* __restrict__ aux1, float* __restrict__ out2,
                          const float* __restrict__ twb, int lane, int gw, int totW) {
    Tw tw = load_tw(twb, lane);
    const int k1 = (int)(__brev((unsigned)lane) >> 26);   // bitrev6
    const float sgn_in = (lane & 1) ? -1.f : 1.f;
#pragma clang loop unroll(disable)
    for (int L = gw; L < NLINES; L += totW) {
        const int img  = L / 320;
        const int l    = L - img * 320;
        const size_t ibase = (size_t)img * 2 * HWc;
        const float* pre = in + ibase + (size_t)l * WID;
        const float* pim = pre + HWc;
        float vr[5], vi[5];
#pragma unroll
        for (int m = 0; m < 5; m++) {
            int n = lane + 64 * m;
            vr[m] = sgn_in * pre[n];
            vi[m] = sgn_in * pim[n];
        }
        float zr[5], zi[5];
        if (EPI == 2) {
#pragma unroll
            for (int k = 0; k < 5; k++) {
                int idxs = 5 * k1 + k + l * WID;
                zr[k] = aux1[ibase + idxs];
                zi[k] = aux1[ibase + HWc + idxs];
            }
        }
        float Cr[5], Ci[5];
        fft320_core<SGN>(vr, vi, Cr, Ci, tw, lane);
        float* qre = out + ibase + (size_t)l * WID;
        float* qim = qre + HWc;
        const float scale = 0.05590169943749474f;  // 1/sqrt(320)
#pragma unroll
        for (int k = 0; k < 5; k++) {
            int kout = 5 * k1 + k;
            float s2 = (kout & 1) ? -scale : scale;
            float re = s2 * Cr[k];
            float im = s2 * Ci[k];
            const int idxs = kout + l * WID;
            if (EPI == 2) {
                re = zr[k] - re;
                im = zi[k] - im;
            }
            qre[kout] = re;
            qim[kout] = im;
            if (EPI == 3) {
                out2[ibase + idxs]       = re;
                out2[ibase + HWc + idxs] = im;
            }
        }
    }
}

// ---------------- column FFT phase (one 8-col tile per block iteration) -----
constexpr int CB   = 8;
constexpr int CPAD = CB + 1;           // 9; gcd(9,32)=1 -> 2-way aliasing free
constexpr int NCTILE = NIMG * (WID / CB);   // 640 tiles

template<int SGN>
__device__ __forceinline__ void fft_line_lds(float (*tile)[320][CPAD], int cl,
                                             int lane, const Tw& tw) {
    float vr[5], vi[5], Cr[5], Ci[5];
    const float sgn_in = (lane & 1) ? -1.f : 1.f;
#pragma unroll
    for (int m = 0; m < 5; m++) {
        int n = lane + 64 * m;
        vr[m] = sgn_in * tile[0][n][cl];
        vi[m] = sgn_in * tile[1][n][cl];
    }
    fft320_core<SGN>(vr, vi, Cr, Ci, tw, lane);
    const int k1 = (int)(__brev((unsigned)lane) >> 26);
    const float scale = 0.05590169943749474f;
#pragma unroll
    for (int k = 0; k < 5; k++) {
        int kout = 5 * k1 + k;
        float s2 = (kout & 1) ? -scale : scale;
        tile[0][kout][cl] = s2 * Cr[k];
        tile[1][kout][cl] = s2 * Ci[k];
    }
}

// MODE 0: single inverse col FFT (init). MODE 1: fwd + k-space DC + inverse.
template<int MODE>
__device__ void col_phase(float (*tile)[320][CPAD],
                          const float* __restrict__ in, float* __restrict__ out,
                          const float* __restrict__ y, const float* __restrict__ mask,
                          const float* __restrict__ twb,
                          int tid, int lane, int wv, int tb) {
    const int bpi = WID / CB;              // 40 tiles per image
    const int img = tb / bpi;
    const int c0  = (tb - img * bpi) * CB;
    const size_t ibase = (size_t)img * 2 * HWc;
    constexpr int C4 = CB / 4;
    constexpr int NE = 320 * C4;           // 640 float4 per component

    __syncthreads();   // protect LDS tile reuse across sequential tiles/phases
#pragma unroll
    for (int comp = 0; comp < 2; comp++) {
        const float* p = in + ibase + (size_t)comp * HWc + c0;
        for (int i = tid; i < NE; i += 512) {
            int row = i >> 1, cg = (i & 1) << 2;
            float4 v = *(const float4*)(p + row * WID + cg);
            float* t = &tile[comp][row][cg];
            t[0] = v.x; t[1] = v.y; t[2] = v.z; t[3] = v.w;
        }
    }
    __syncthreads();

    if (MODE == 1) {
        Tw twf = load_tw(twb, lane);              // forward table
        fft_line_lds<-1>(tile, wv, lane, twf);
        __syncthreads();
        const float* pm  = mask + (size_t)img * HWc + c0;
        const float* pyr = y + ibase + c0;
        const float* pyi = y + ibase + HWc + c0;
        for (int i = tid; i < NE; i += 512) {
            int row = i >> 1, cg = (i & 1) << 2;
            float4 m4 = *(const float4*)(pm  + row * WID + cg);
            float4 yr = *(const float4*)(pyr + row * WID + cg);
            float4 yi = *(const float4*)(pyi + row * WID + cg);
            float* tr = &tile[0][row][cg];
            float* ti = &tile[1][row][cg];
            tr[0] = m4.x * (m4.x * tr[0] - yr.x);
            tr[1] = m4.y * (m4.y * tr[1] - yr.y);
            tr[2] = m4.z * (m4.z * tr[2] - yr.z);
            tr[3] = m4.w * (m4.w * tr[3] - yr.w);
            ti[0] = m4.x * (m4.x * ti[0] - yi.x);
            ti[1] = m4.y * (m4.y * ti[1] - yi.y);
            ti[2] = m4.z * (m4.z * ti[2] - yi.z);
            ti[3] = m4.w * (m4.w * ti[3] - yi.w);
        }
        __syncthreads();
    }
    {
        Tw twi = load_tw(twb + 14 * 64, lane);    // inverse table
        fft_line_lds<1>(tile, wv, lane, twi);
    }
    __syncthreads();
#pragma unroll
    for (int comp = 0; comp < 2; comp++) {
        float* p = out + ibase + (size_t)comp * HWc + c0;
        for (int i = tid; i < NE; i += 512) {
            int row = i >> 1, cg = (i & 1) << 2;
            const float* t = &tile[comp][row][cg];
            *(float4*)(p + row * WID + cg) = make_float4(t[0], t[1], t[2], t[3]);
        }
    }
}

// ============ TV prox + 3-level Haar + FISTA (R12 geometry, verbatim) =======
constexpr int HALO = 4;
constexpr int TIR = 8;                  // interior rows
constexpr int TVR = TIR + 2 * HALO;     // 16 rows per tile
constexpr int TIC = 48;                 // interior cols
constexpr int TCOLS = 7;                // ceil(320/48)
constexpr int TROWS = WID / TIR;        // 40
constexpr int TPS = TROWS * TCOLS;      // 280 tiles per slice
constexpr int NEDGE = 2 * TCOLS + 2 * (TROWS - 2);   // 90 edge tiles/slice
constexpr int NTVW = NSL * TPS;         // 8960 tile-waves

template<bool EDGE>
__device__ __forceinline__ void tv_core(const float* __restrict__ g, int gi0, int gj,
                                        float (&uf)[TIR]) {
    float z_[TVR], px_[TVR], py_[TVR];
    const bool colin = !EDGE || ((unsigned)gj < (unsigned)WID);
#pragma unroll
    for (int r = 0; r < TVR; r++) {
        int gi = gi0 + r;
        float v = 0.f;
        if (!EDGE) {
            v = g[gi * WID + gj];
        } else {
            bool in = colin && ((unsigned)gi < (unsigned)WID);
            if (in) v = g[gi * WID + gj];
        }
        z_[r] = v; px_[r] = 0.f; py_[r] = 0.f;
    }
    const bool gj_le0 = EDGE && (gj <= 0);
    const bool gj_hi  = EDGE && (gj >= WID - 1);
    const bool gx_on  = !EDGE || (gj < WID - 1);

#pragma clang loop unroll(disable)
    for (int it = 0; it < 5; it++) {
        float u_[TVR], sh[TVR];
#pragma unroll
        for (int r = 0; r < TVR; r++) sh[r] = __shfl_up(px_[r], 1);
#pragma unroll
        for (int r = 0; r < TVR; r++) {
            float divx, divy;
            if (!EDGE) {
                divx = px_[r] - sh[r];
                divy = (r > 0) ? py_[r] - py_[r - 1] : 0.f;
            } else {
                int gi = gi0 + r;
                divx = gj_le0 ? px_[r] : (gj_hi ? -sh[r] : px_[r] - sh[r]);
                float pym = (r > 0) ? py_[r - 1] : py_[0];
                divy = (gi <= 0) ? py_[r]
                     : ((gi >= WID - 1) ? -pym : py_[r] - pym);
            }
            u_[r] = z_[r] - LAM_TV * (divx + divy);
        }
#pragma unroll
        for (int r = 0; r < TVR; r++) sh[r] = __shfl_down(u_[r], 1);
#pragma unroll
        for (int r = 0; r < TVR; r++) {
            float gx, gy;
            if (!EDGE) {
                gx = sh[r] - u_[r];
                gy = (r < TVR - 1) ? u_[r + 1] - u_[r] : 0.f;
            } else {
                int gi = gi0 + r;
                float ub = (r < TVR - 1) ? u_[r + 1] : u_[r];
                gx = gx_on ? sh[r] - u_[r] : 0.f;
                gy = (gi < WID - 1 && r < TVR - 1) ? ub - u_[r] : 0.f;
            }
            float px = fmaf(0.25f, gx, px_[r]);
            float py = fmaf(0.25f, gy, py_[r]);
            float n2 = fmaf(px, px, fmaf(py, py, 1e-8f));
            float inv = fminf(fast_rsq(n2), 1.f);
            px_[r] = px * inv;
            py_[r] = py * inv;
        }
    }
    float shf[TIR];
#pragma unroll
    for (int r = HALO; r < TVR - HALO; r++) shf[r - HALO] = __shfl_up(px_[r], 1);
#pragma unroll
    for (int r = HALO; r < TVR - HALO; r++) {
        float pxm = shf[r - HALO];
        float divx, divy;
        if (!EDGE) {
            divx = px_[r] - pxm;
            divy = py_[r] - py_[r - 1];
        } else {
            int gi = gi0 + r;
            divx = gj_le0 ? px_[r] : (gj_hi ? -pxm : px_[r] - pxm);
            divy = (gi <= 0) ? py_[r]
                 : ((gi >= WID - 1) ? -py_[r - 1] : py_[r] - py_[r - 1]);
        }
        uf[r - HALO] = z_[r] - LAM_TV * (divx + divy);
    }
}

__device__ void tv_phase(const float* __restrict__ zs, float* __restrict__ x,
                         float* __restrict__ z, float beta, bool storez,
                         int lane, int gw, int totW) {
#pragma clang loop unroll(disable)
    for (int w = gw; w < NTVW; w += totW) {
        const int sl   = w / TPS;
        const int rem  = w - sl * TPS;
        int trow, tcol;
        if (rem < 2 * TCOLS) {
            trow = (rem < TCOLS) ? 0 : (TROWS - 1);
            tcol = (rem < TCOLS) ? rem : rem - TCOLS;
        } else if (rem < NEDGE) {
            int e = rem - 2 * TCOLS;
            trow = 1 + (e % (TROWS - 2));
            tcol = (e < TROWS - 2) ? 0 : (TCOLS - 1);
        } else {
            int i2 = rem - NEDGE;
            trow = 1 + i2 / (TCOLS - 2);
            tcol = 1 + i2 % (TCOLS - 2);
        }
        const int gi0  = trow * TIR - HALO;
        const int gj   = tcol * TIC - 8 + lane;
        const float* g = zs + (size_t)sl * HWc;

        float uf[TIR];
        if (rem >= NEDGE) tv_core<false>(g, gi0, gj, uf);
        else              tv_core<true >(g, gi0, gj, uf);

        const float sc1 = (lane & 1) ? -1.f : 1.f;
        const float sc2 = (lane & 2) ? -1.f : 1.f;
        const float sc3 = (lane & 4) ? -1.f : 1.f;

        float ll1[4], lh1[4], hl1[4], hh1[4];
#pragma unroll
        for (int k = 0; k < 4; k++) {
            float a0 = uf[2 * k], a1 = uf[2 * k + 1];
            float n0 = __shfl_xor(a0, 1), n1 = __shfl_xor(a1, 1);
            float h0 = a0 + n0, d0 = sc1 * (a0 - n0);
            float h1 = a1 + n1, d1 = sc1 * (a1 - n1);
            ll1[k] = (h0 + h1) * 0.5f;
            lh1[k] = softt((h0 - h1) * 0.5f);
            hl1[k] = softt((d0 + d1) * 0.5f);
            hh1[k] = softt((d0 - d1) * 0.5f);
        }
        float ll2[2], lh2[2], hl2[2], hh2[2];
#pragma unroll
        for (int k = 0; k < 2; k++) {
            float a0 = ll1[2 * k], a1 = ll1[2 * k + 1];
            float n0 = __shfl_xor(a0, 2), n1 = __shfl_xor(a1, 2);
            float h0 = a0 + n0, d0 = sc2 * (a0 - n0);
            float h1 = a1 + n1, d1 = sc2 * (a1 - n1);
            ll2[k] = (h0 + h1) * 0.5f;
            lh2[k] = softt((h0 - h1) * 0.5f);
            hl2[k] = softt((d0 + d1) * 0.5f);
            hh2[k] = softt((d0 - d1) * 0.5f);
        }
        float ll3, lh3, hl3, hh3;
        {
            float a0 = ll2[0], a1 = ll2[1];
            float n0 = __shfl_xor(a0, 4), n1 = __shfl_xor(a1, 4);
            float h0 = a0 + n0, d0 = sc3 * (a0 - n0);
            float h1 = a1 + n1, d1 = sc3 * (a1 - n1);
            ll3 = (h0 + h1) * 0.5f;
            lh3 = softt((h0 - h1) * 0.5f);
            hl3 = softt((d0 + d1) * 0.5f);
            hh3 = softt((d0 - d1) * 0.5f);
        }
        float l2p[2];
        l2p[0] = 0.5f * ((ll3 + lh3) + sc3 * (hl3 + hh3));
        l2p[1] = 0.5f * ((ll3 - lh3) + sc3 * (hl3 - hh3));
        float l1p[4];
#pragma unroll
        for (int k = 0; k < 2; k++) {
            l1p[2 * k]     = 0.5f * ((l2p[k] + lh2[k]) + sc2 * (hl2[k] + hh2[k]));
            l1p[2 * k + 1] = 0.5f * ((l2p[k] - lh2[k]) + sc2 * (hl2[k] - hh2[k]));
        }
        float xn[TIR];
#pragma unroll
        for (int k = 0; k < 4; k++) {
            xn[2 * k]     = 0.5f * ((l1p[k] + lh1[k]) + sc1 * (hl1[k] + hh1[k]));
            xn[2 * k + 1] = 0.5f * ((l1p[k] - lh1[k]) + sc1 * (hl1[k] - hh1[k]));
        }

        const bool wcol = (lane >= 8) && (lane < 56) && ((unsigned)gj < (unsigned)WID);
        float* px = x + (size_t)sl * HWc;
        float* pz = z + (size_t)sl * HWc;
        const int gi_int0 = trow * TIR;
#pragma unroll
        for (int i = 0; i < TIR; i++) {
            int off = (gi_int0 + i) * WID + gj;
            if (storez) {
                float xo = wcol ? px[off] : 0.f;
                float zn = xn[i] + beta * (xn[i] - xo);
                if (wcol) {
                    px[off] = xn[i];
                    pz[off] = zn;
                }
            } else {
                if (wcol) px[off] = xn[i];
            }
        }
    }
}

// ---------------- device-scope grid barrier (sense-reversing) ---------------
// Requires cnt==0 at first use (build_tw zeroes it — ws is POISONED by the
// harness, never assume zero). Tolerates arbitrary initial gen. cnt returns
// to 0 after each barrier, so repeated graph replays are safe.
__device__ __forceinline__ void gbar(unsigned* bar, int nblk) {
    __syncthreads();
    if (threadIdx.x == 0) {
        __threadfence();                              // release our writes
        unsigned* cnt = bar;
        unsigned* gen = bar + 1;
        unsigned g = __hip_atomic_load(gen, __ATOMIC_RELAXED, __HIP_MEMORY_SCOPE_AGENT);
        unsigned a = __hip_atomic_fetch_add(cnt, 1u, __ATOMIC_RELAXED, __HIP_MEMORY_SCOPE_AGENT);
        if (a == (unsigned)nblk - 1u) {
            __hip_atomic_store(cnt, 0u, __ATOMIC_RELAXED, __HIP_MEMORY_SCOPE_AGENT);
            __hip_atomic_fetch_add(gen, 1u, __ATOMIC_RELEASE, __HIP_MEMORY_SCOPE_AGENT);
        } else {
            while (__hip_atomic_load(gen, __ATOMIC_RELAXED, __HIP_MEMORY_SCOPE_AGENT) == g)
                __builtin_amdgcn_s_sleep(2);
        }
        __threadfence();                              // acquire others' writes
    }
    __syncthreads();
}

// ---------------- the persistent mega-kernel --------------------------------
// 512 threads (8 waves); __launch_bounds__(512,4) caps VGPR at 128 so 2
// blocks/CU are guaranteed (m69 occupancy steps; LDS 23KB allows 6). Grid
// sized by the host from the occupancy API, so co-residency (no-deadlock)
// holds by construction; no block retires before all reach each barrier.
__global__ __launch_bounds__(512, 4) void mega(
        const float* __restrict__ y, const float* __restrict__ mask,
        float* __restrict__ x, float* __restrict__ z,
        float* __restrict__ t1, float* __restrict__ t2,
        const float* __restrict__ twb, unsigned* bar, int nblk) {
    __shared__ float tile[2][320][CPAD];   // 23 KB (col phases only)
    const int tid  = threadIdx.x;
    const int lane = tid & 63;
    const int wv   = __builtin_amdgcn_readfirstlane(tid >> 6);   // 0..7
    const int blk  = blockIdx.x;
    const int gw   = blk * 8 + wv;
    const int totW = nblk * 8;
    const float* twF = twb;
    const float* twI = twb + 14 * 64;

    // init: x0 = ifft2c(y): col-inverse then row-inverse (dual store x,z)
#pragma clang loop unroll(disable)
    for (int tb = blk; tb < NCTILE; tb += nblk)
        col_phase<0>(tile, y, t1, nullptr, nullptr, twb, tid, lane, wv, tb);
    gbar(bar, nblk);
    row_phase<1, 3>(t1, x, nullptr, z, twI, lane, gw, totW);
    gbar(bar, nblk);

    float t = 1.f;
#pragma clang loop unroll(disable)
    for (int it = 0; it < 15; it++) {
        row_phase<-1, 0>(z, t1, nullptr, nullptr, twF, lane, gw, totW);
        gbar(bar, nblk);
#pragma clang loop unroll(disable)
        for (int tb = blk; tb < NCTILE; tb += nblk)
            col_phase<1>(tile, t1, t2, y, mask, twb, tid, lane, wv, tb);
        gbar(bar, nblk);
        row_phase<1, 2>(t2, t1, z, nullptr, twI, lane, gw, totW);
        gbar(bar, nblk);
        float tn   = (1.f + sqrtf(1.f + 4.f * t * t)) * 0.5f;
        float beta = (t - 1.f) / tn;
        t = tn;
        tv_phase(t1, x, z, beta, it < 14, lane, gw, totW);
        if (it < 14) gbar(bar, nblk);
    }
}

// ---------------- host orchestration ----------------
extern "C" void kernel_launch(void* const* d_in, const int* in_sizes, int n_in,
                              void* d_out, int out_size, void* d_ws, size_t ws_size,
                              hipStream_t stream) {
    const float* y    = (const float*)d_in[0];
    const float* mask = (const float*)d_in[1];
    float* x = (float*)d_out;

    float* ws = (float*)d_ws;
    float* z  = ws;                       // NTOT
    float* t1 = ws + (size_t)NTOT;        // NTOT
    float* t2 = ws + 2 * (size_t)NTOT;    // NTOT
    float* tw = ws + 3 * (size_t)NTOT;    // 2*14*64 floats twiddle tables
    unsigned* bar = (unsigned*)(tw + 2 * 14 * 64);   // {cnt, gen}

    // Deadlock-proof grid sizing: never launch more blocks than can be
    // co-resident. Host-side query only — graph-capture-safe.
    int nper = 1;
    (void)hipOccupancyMaxActiveBlocksPerMultiprocessor(&nper, mega, 512, 0);
    if (nper < 1) nper = 1;
    int nblk = nper * 256;                // 256 CUs on MI355X
    if (nblk > 512) nblk = 512;           // >512 adds nothing (640 col tiles)

    build_tw<<<1, 64, 0, stream>>>(tw, bar);
    mega<<<nblk, 512, 0, stream>>>(y, mask, x, z, t1, t2, tw, bar, nblk);
    (void)in_sizes; (void)n_in; (void)out_size; (void)ws_size;
}

// Round 5
// 1439.497 us; speedup vs baseline: 2.7336x; 2.7336x over previous
//
#include <hip/hip_runtime.h>
#include <math.h>

constexpr int WID  = 320;
constexpr int HWc  = 320 * 320;        // 102400
constexpr int NIMG = 16;
constexpr int NSL  = 32;               // B*C slices for TV/DWT
constexpr int NTOT = NIMG * 2 * HWc;   // 3276800 floats per full array
constexpr float LAM_TV  = 0.005f;
constexpr float LAM_WAV = 0.005f;

// R17: revert to R12 multi-kernel (mega arc R15/R16 was -3.2x: 61 global
// barriers + grid-limited 50% occupancy + launch_bounds-forced TV spills to
// scratch at VGPR=64). New: fuse TV(it)+rowF(it+1) — TV emits z_new in 8-row
// FULL-WIDTH strips (LDS), rowF is row-local => zero halo recompute. Saves 14
// dispatches, rowF's 13MB/iter z read, and cuts TV input amplification
// 2.67x -> 2.0x (col halo now free via LDS strip). TV tile + FFT math are
// bit-identical to R12.

__device__ __forceinline__ float softt(float v) {
    float a = fmaxf(fabsf(v) - LAM_WAV, 0.f);
    return copysignf(a, v);
}

__device__ __forceinline__ float fast_rsq(float x) {
    float r;
    asm volatile("v_rsq_f32 %0, %1" : "=v"(r) : "v"(x));
    return r;
}

// ================= 320-point FFT core ======================================
struct Tw { float tc, ts; float stc[6], sts[6]; };

__global__ void build_tw(float* tb) {
    const int lane = threadIdx.x;   // 64 threads
#pragma unroll
    for (int g = 0; g < 2; g++) {
        const float sgn = g ? 1.f : -1.f;
        float* p = tb + g * 14 * 64;
        float ts, tc;
        __sincosf(sgn * 6.283185307179586f * (float)lane / 320.f, &ts, &tc);
        p[lane] = tc; p[64 + lane] = ts;
#pragma unroll
        for (int s = 0; s < 6; s++) {
            int h = 32 >> s;
            int j = lane & (h - 1);
            float ang = sgn * 3.14159265358979323f * (float)j / (float)h;
            float ss, cc;
            __sincosf(ang, &ss, &cc);
            p[(2 + s) * 64 + lane] = cc;
            p[(8 + s) * 64 + lane] = ss;
        }
    }
}

__device__ __forceinline__ Tw load_tw(const float* __restrict__ tb, int lane) {
    Tw tw;
    tw.tc = tb[lane];
    tw.ts = tb[64 + lane];
#pragma unroll
    for (int s = 0; s < 6; s++) {
        tw.stc[s] = tb[(2 + s) * 64 + lane];
        tw.sts[s] = tb[(8 + s) * 64 + lane];
    }
    return tw;
}

template<int SGN>
__device__ __forceinline__ void fft320_core(const float (&vr)[5], const float (&vi)[5],
                                            float (&Cr)[5], float (&Ci)[5],
                                            const Tw& tw, int lane) {
    const float cw1 = 0.30901699437494745f, sw1 = 0.9510565162951535f;
    const float cw2 = -0.8090169943749475f, sw2 = 0.5877852522924731f;
    const float cwt[5] = {1.f, cw1, cw2, cw2, cw1};
    const float swt[5] = {0.f, sw1, sw2, -sw2, -sw1};
    Cr[0] = vr[0] + vr[1] + vr[2] + vr[3] + vr[4];
    Ci[0] = vi[0] + vi[1] + vi[2] + vi[3] + vi[4];
#pragma unroll
    for (int k = 1; k < 5; k++) {
        float ar = vr[0], ai = vi[0];
#pragma unroll
        for (int m = 1; m < 5; m++) {
            int j = (m * k) % 5;
            float wr_ = cwt[j], wi_ = (float)SGN * swt[j];
            ar += vr[m] * wr_ - vi[m] * wi_;
            ai += vr[m] * wi_ + vi[m] * wr_;
        }
        Cr[k] = ar; Ci[k] = ai;
    }
    float twr = 1.f, twi = 0.f;
#pragma unroll
    for (int k = 1; k < 5; k++) {
        float nr = twr * tw.tc - twi * tw.ts;
        twi = twr * tw.ts + twi * tw.tc;
        twr = nr;
        float r = Cr[k] * twr - Ci[k] * twi;
        Ci[k]   = Cr[k] * twi + Ci[k] * twr;
        Cr[k]   = r;
    }
#pragma unroll
    for (int s = 0; s < 6; s++) {
        int h = 32 >> s;
        bool up = (lane & h) != 0;
#pragma unroll
        for (int k = 0; k < 5; k++) {
            float orr = __shfl_xor(Cr[k], h);
            float oii = __shfl_xor(Ci[k], h);
            if (up) {
                float dr = orr - Cr[k], di = oii - Ci[k];
                Cr[k] = dr * tw.stc[s] - di * tw.sts[s];
                Ci[k] = dr * tw.sts[s] + di * tw.stc[s];
            } else {
                Cr[k] += orr;
                Ci[k] += oii;
            }
        }
    }
}

// ---------------- row FFT pass (1 line/wave, 5120 waves = 5/SIMD) -----------
// EPI: 0 = plain store
//      2 = residual store: out = aux1 - val   (aux1 = z, PREFETCHED at entry)
//      3 = dual store:     out and out2 both get val
template<int SGN, int EPI>
__global__ __launch_bounds__(256) void fft_row(const float* __restrict__ in,
                                               float* __restrict__ out,
                                               const float* __restrict__ aux1,
                                               float* __restrict__ out2,
                                               const float* __restrict__ twb) {
    const int lane = threadIdx.x & 63;
    const int wv   = threadIdx.x >> 6;
    const int L    = blockIdx.x * 4 + wv;
    const int img  = L / 320;
    const int l    = L - img * 320;
    const size_t ibase = (size_t)img * 2 * HWc;
    const float* pre = in + ibase + (size_t)l * WID;
    const float* pim = pre + HWc;
    const int k1 = (int)(__brev((unsigned)lane) >> 26);   // bitrev6

    Tw tw = load_tw(twb, lane);

    float vr[5], vi[5];
    const float sgn_in = (lane & 1) ? -1.f : 1.f;
#pragma unroll
    for (int m = 0; m < 5; m++) {
        int n = lane + 64 * m;
        vr[m] = sgn_in * pre[n];
        vi[m] = sgn_in * pim[n];
    }
    float zr[5], zi[5];
    if (EPI == 2) {
#pragma unroll
        for (int k = 0; k < 5; k++) {
            int idxs = 5 * k1 + k + l * WID;
            zr[k] = aux1[ibase + idxs];
            zi[k] = aux1[ibase + HWc + idxs];
        }
    }

    float Cr[5], Ci[5];
    fft320_core<SGN>(vr, vi, Cr, Ci, tw, lane);

    float* qre = out + ibase + (size_t)l * WID;
    float* qim = qre + HWc;
    const float scale = 0.05590169943749474f;  // 1/sqrt(320)
#pragma unroll
    for (int k = 0; k < 5; k++) {
        int kout = 5 * k1 + k;
        float s2 = (kout & 1) ? -scale : scale;
        float re = s2 * Cr[k];
        float im = s2 * Ci[k];
        const int idxs = kout + l * WID;
        if (EPI == 2) {
            re = zr[k] - re;
            im = zi[k] - im;
        }
        qre[kout] = re;
        qim[kout] = im;
        if (EPI == 3) {
            out2[ibase + idxs]       = re;
            out2[ibase + HWc + idxs] = im;
        }
    }
}

// ---------------- fused column FFT kernel (LDS-transposed, high-TLP) --------
constexpr int CB   = 8;        // columns per block
constexpr int CPAD = CB + 1;   // 9

template<int SGN>
__device__ __forceinline__ void fft_line_lds(float (*tile)[320][CPAD], int cl,
                                             int lane, const Tw& tw) {
    float vr[5], vi[5], Cr[5], Ci[5];
    const float sgn_in = (lane & 1) ? -1.f : 1.f;
#pragma unroll
    for (int m = 0; m < 5; m++) {
        int n = lane + 64 * m;
        vr[m] = sgn_in * tile[0][n][cl];
        vi[m] = sgn_in * tile[1][n][cl];
    }
    fft320_core<SGN>(vr, vi, Cr, Ci, tw, lane);
    const int k1 = (int)(__brev((unsigned)lane) >> 26);
    const float scale = 0.05590169943749474f;
#pragma unroll
    for (int k = 0; k < 5; k++) {
        int kout = 5 * k1 + k;
        float s2 = (kout & 1) ? -scale : scale;
        tile[0][kout][cl] = s2 * Cr[k];
        tile[1][kout][cl] = s2 * Ci[k];
    }
}

template<int MODE>
__global__ __launch_bounds__(512) void fft_col(const float* __restrict__ in,
                                               float* __restrict__ out,
                                               const float* __restrict__ y,
                                               const float* __restrict__ mask,
                                               const float* __restrict__ twb) {
    __shared__ float tile[2][320][CPAD];   // 23 KB
    const int tid = threadIdx.x;
    const int bpi = WID / CB;              // 40 blocks per image
    const int img = blockIdx.x / bpi;
    const int c0  = (blockIdx.x - img * bpi) * CB;
    const size_t ibase = (size_t)img * 2 * HWc;
    constexpr int C4 = CB / 4;
    constexpr int NE = 320 * C4;           // 640 float4 per component

#pragma unroll
    for (int comp = 0; comp < 2; comp++) {
        const float* p = in + ibase + (size_t)comp * HWc + c0;
        for (int i = tid; i < NE; i += 512) {
            int row = i >> 1, cg = (i & 1) << 2;
            float4 v = *(const float4*)(p + row * WID + cg);
            float* t = &tile[comp][row][cg];
            t[0] = v.x; t[1] = v.y; t[2] = v.z; t[3] = v.w;
        }
    }
    __syncthreads();

    const int lane = tid & 63;
    const int wv   = tid >> 6;

    if (MODE == 1) {
        Tw twf = load_tw(twb, lane);
        fft_line_lds<-1>(tile, wv, lane, twf);
        __syncthreads();
        const float* pm  = mask + (size_t)img * HWc + c0;
        const float* pyr = y + ibase + c0;
        const float* pyi = y + ibase + HWc + c0;
        for (int i = tid; i < NE; i += 512) {
            int row = i >> 1, cg = (i & 1) << 2;
            float4 m4 = *(const float4*)(pm  + row * WID + cg);
            float4 yr = *(const float4*)(pyr + row * WID + cg);
            float4 yi = *(const float4*)(pyi + row * WID + cg);
            float* tr = &tile[0][row][cg];
            float* ti = &tile[1][row][cg];
            tr[0] = m4.x * (m4.x * tr[0] - yr.x);
            tr[1] = m4.y * (m4.y * tr[1] - yr.y);
            tr[2] = m4.z * (m4.z * tr[2] - yr.z);
            tr[3] = m4.w * (m4.w * tr[3] - yr.w);
            ti[0] = m4.x * (m4.x * ti[0] - yi.x);
            ti[1] = m4.y * (m4.y * ti[1] - yi.y);
            ti[2] = m4.z * (m4.z * ti[2] - yi.z);
            ti[3] = m4.w * (m4.w * ti[3] - yi.w);
        }
        __syncthreads();
    }
    {
        Tw twi = load_tw(twb + 14 * 64, lane);
        fft_line_lds<1>(tile, wv, lane, twi);
    }
    __syncthreads();
#pragma unroll
    for (int comp = 0; comp < 2; comp++) {
        float* p = out + ibase + (size_t)comp * HWc + c0;
        for (int i = tid; i < NE; i += 512) {
            int row = i >> 1, cg = (i & 1) << 2;
            const float* t = &tile[comp][row][cg];
            *(float4*)(p + row * WID + cg) = make_float4(t[0], t[1], t[2], t[3]);
        }
    }
}

// ============ TV prox + 3-level Haar + FISTA (R12 geometry) ================
constexpr int HALO = 4;
constexpr int TIR = 8;                  // interior rows
constexpr int TVR = TIR + 2 * HALO;     // 16 rows per tile
constexpr int TIC = 48;                 // interior cols
constexpr int TCOLS = 7;                // ceil(320/48)
constexpr int TROWS = WID / TIR;        // 40
constexpr int TPS = TROWS * TCOLS;      // 280 tiles per slice
constexpr int NEDGE = 2 * TCOLS + 2 * (TROWS - 2);   // 90 edge tiles/slice
constexpr int SPAD = WID + 1;           // 321, LDS strip stride

// ---- TV core reading from an LDS full-width strip (rows 0..15 = gi0..) ----
// Bit-identical math to R12's global-read tv_core: LDS rows are zero-filled
// for out-of-image gi, and colin guards out-of-image gj.
template<bool EDGE>
__device__ __forceinline__ void tv_core_lds(const float (*zst)[SPAD], int gi0, int gj,
                                            float (&uf)[TIR]) {
    float z_[TVR], px_[TVR], py_[TVR];
    const bool colin = !EDGE || ((unsigned)gj < (unsigned)WID);
#pragma unroll
    for (int r = 0; r < TVR; r++) {
        float v = 0.f;
        if (!EDGE) v = zst[r][gj];
        else if (colin) v = zst[r][gj];   // rows OOB are zero-filled in LDS
        z_[r] = v; px_[r] = 0.f; py_[r] = 0.f;
    }
    const bool gj_le0 = EDGE && (gj <= 0);
    const bool gj_hi  = EDGE && (gj >= WID - 1);
    const bool gx_on  = !EDGE || (gj < WID - 1);

#pragma clang loop unroll(disable)
    for (int it = 0; it < 5; it++) {
        float u_[TVR], sh[TVR];
#pragma unroll
        for (int r = 0; r < TVR; r++) sh[r] = __shfl_up(px_[r], 1);
#pragma unroll
        for (int r = 0; r < TVR; r++) {
            float divx, divy;
            if (!EDGE) {
                divx = px_[r] - sh[r];
                divy = (r > 0) ? py_[r] - py_[r - 1] : 0.f;
            } else {
                int gi = gi0 + r;
                divx = gj_le0 ? px_[r] : (gj_hi ? -sh[r] : px_[r] - sh[r]);
                float pym = (r > 0) ? py_[r - 1] : py_[0];
                divy = (gi <= 0) ? py_[r]
                     : ((gi >= WID - 1) ? -pym : py_[r] - pym);
            }
            u_[r] = z_[r] - LAM_TV * (divx + divy);
        }
#pragma unroll
        for (int r = 0; r < TVR; r++) sh[r] = __shfl_down(u_[r], 1);
#pragma unroll
        for (int r = 0; r < TVR; r++) {
            float gx, gy;
            if (!EDGE) {
                gx = sh[r] - u_[r];
                gy = (r < TVR - 1) ? u_[r + 1] - u_[r] : 0.f;
            } else {
                int gi = gi0 + r;
                float ub = (r < TVR - 1) ? u_[r + 1] : u_[r];
                gx = gx_on ? sh[r] - u_[r] : 0.f;
                gy = (gi < WID - 1 && r < TVR - 1) ? ub - u_[r] : 0.f;
            }
            float px = fmaf(0.25f, gx, px_[r]);
            float py = fmaf(0.25f, gy, py_[r]);
            float n2 = fmaf(px, px, fmaf(py, py, 1e-8f));
            float inv = fminf(fast_rsq(n2), 1.f);
            px_[r] = px * inv;
            py_[r] = py * inv;
        }
    }
    float shf[TIR];
#pragma unroll
    for (int r = HALO; r < TVR - HALO; r++) shf[r - HALO] = __shfl_up(px_[r], 1);
#pragma unroll
    for (int r = HALO; r < TVR - HALO; r++) {
        float pxm = shf[r - HALO];
        float divx, divy;
        if (!EDGE) {
            divx = px_[r] - pxm;
            divy = py_[r] - py_[r - 1];
        } else {
            int gi = gi0 + r;
            divx = gj_le0 ? px_[r] : (gj_hi ? -pxm : px_[r] - pxm);
            divy = (gi <= 0) ? py_[r]
                 : ((gi >= WID - 1) ? -py_[r - 1] : py_[r] - py_[r - 1]);
        }
        uf[r - HALO] = z_[r] - LAM_TV * (divx + divy);
    }
}

// Wavelet + soft-threshold + inverse (R12 verbatim), returns xn[8]
__device__ __forceinline__ void haar3(const float (&uf)[TIR], int lane, float (&xn)[TIR]) {
    const float sc1 = (lane & 1) ? -1.f : 1.f;
    const float sc2 = (lane & 2) ? -1.f : 1.f;
    const float sc3 = (lane & 4) ? -1.f : 1.f;

    float ll1[4], lh1[4], hl1[4], hh1[4];
#pragma unroll
    for (int k = 0; k < 4; k++) {
        float a0 = uf[2 * k], a1 = uf[2 * k + 1];
        float n0 = __shfl_xor(a0, 1), n1 = __shfl_xor(a1, 1);
        float h0 = a0 + n0, d0 = sc1 * (a0 - n0);
        float h1 = a1 + n1, d1 = sc1 * (a1 - n1);
        ll1[k] = (h0 + h1) * 0.5f;
        lh1[k] = softt((h0 - h1) * 0.5f);
        hl1[k] = softt((d0 + d1) * 0.5f);
        hh1[k] = softt((d0 - d1) * 0.5f);
    }
    float ll2[2], lh2[2], hl2[2], hh2[2];
#pragma unroll
    for (int k = 0; k < 2; k++) {
        float a0 = ll1[2 * k], a1 = ll1[2 * k + 1];
        float n0 = __shfl_xor(a0, 2), n1 = __shfl_xor(a1, 2);
        float h0 = a0 + n0, d0 = sc2 * (a0 - n0);
        float h1 = a1 + n1, d1 = sc2 * (a1 - n1);
        ll2[k] = (h0 + h1) * 0.5f;
        lh2[k] = softt((h0 - h1) * 0.5f);
        hl2[k] = softt((d0 + d1) * 0.5f);
        hh2[k] = softt((d0 - d1) * 0.5f);
    }
    float ll3, lh3, hl3, hh3;
    {
        float a0 = ll2[0], a1 = ll2[1];
        float n0 = __shfl_xor(a0, 4), n1 = __shfl_xor(a1, 4);
        float h0 = a0 + n0, d0 = sc3 * (a0 - n0);
        float h1 = a1 + n1, d1 = sc3 * (a1 - n1);
        ll3 = (h0 + h1) * 0.5f;
        lh3 = softt((h0 - h1) * 0.5f);
        hl3 = softt((d0 + d1) * 0.5f);
        hh3 = softt((d0 - d1) * 0.5f);
    }
    float l2p[2];
    l2p[0] = 0.5f * ((ll3 + lh3) + sc3 * (hl3 + hh3));
    l2p[1] = 0.5f * ((ll3 - lh3) + sc3 * (hl3 - hh3));
    float l1p[4];
#pragma unroll
    for (int k = 0; k < 2; k++) {
        l1p[2 * k]     = 0.5f * ((l2p[k] + lh2[k]) + sc2 * (hl2[k] + hh2[k]));
        l1p[2 * k + 1] = 0.5f * ((l2p[k] - lh2[k]) + sc2 * (hl2[k] - hh2[k]));
    }
#pragma unroll
    for (int k = 0; k < 4; k++) {
        xn[2 * k]     = 0.5f * ((l1p[k] + lh1[k]) + sc1 * (hl1[k] + hh1[k]));
        xn[2 * k + 1] = 0.5f * ((l1p[k] - lh1[k]) + sc1 * (hl1[k] - hh1[k]));
    }
}

// ---- standalone TV kernel (R12 structure, last iteration only, no z store) -
__global__ __launch_bounds__(256) void tv_wav_last(const float* __restrict__ zs,
                                                   float* __restrict__ x) {
    const int lane = threadIdx.x & 63;
    const int wv   = __builtin_amdgcn_readfirstlane(threadIdx.x >> 6);
    const int w    = blockIdx.x * 4 + wv;           // 32*280 = 8960 waves
    const int sl   = w / TPS;
    const int rem  = w - sl * TPS;
    int trow, tcol;
    if (rem < 2 * TCOLS) {
        trow = (rem < TCOLS) ? 0 : (TROWS - 1);
        tcol = (rem < TCOLS) ? rem : rem - TCOLS;
    } else if (rem < NEDGE) {
        int e = rem - 2 * TCOLS;
        trow = 1 + (e % (TROWS - 2));
        tcol = (e < TROWS - 2) ? 0 : (TCOLS - 1);
    } else {
        int i2 = rem - NEDGE;
        trow = 1 + i2 / (TCOLS - 2);
        tcol = 1 + i2 % (TCOLS - 2);
    }
    const int gi0  = trow * TIR - HALO;
    const int gj   = tcol * TIC - 8 + lane;
    const float* g = zs + (size_t)sl * HWc;

    // emulate the LDS-strip read path with a local strip gathered from global
    // (identical values: rows OOB -> 0)
    __shared__ float dummy;   // keep signature simple; direct global variant:
    (void)dummy;
    float uf[TIR];
    {
        // local reconstruction of tv_core on global memory (R12 verbatim)
        float z_[TVR], px_[TVR], py_[TVR];
        const bool edge = (trow == 0) || (trow == TROWS - 1) ||
                          (tcol == 0) || (tcol == TCOLS - 1);
        const bool colin = (unsigned)gj < (unsigned)WID;
        if (!edge) {
#pragma unroll
            for (int r = 0; r < TVR; r++) {
                z_[r] = g[(gi0 + r) * WID + gj];
                px_[r] = 0.f; py_[r] = 0.f;
            }
#pragma clang loop unroll(disable)
            for (int it = 0; it < 5; it++) {
                float u_[TVR], sh[TVR];
#pragma unroll
                for (int r = 0; r < TVR; r++) sh[r] = __shfl_up(px_[r], 1);
#pragma unroll
                for (int r = 0; r < TVR; r++) {
                    float divx = px_[r] - sh[r];
                    float divy = (r > 0) ? py_[r] - py_[r - 1] : 0.f;
                    u_[r] = z_[r] - LAM_TV * (divx + divy);
                }
#pragma unroll
                for (int r = 0; r < TVR; r++) sh[r] = __shfl_down(u_[r], 1);
#pragma unroll
                for (int r = 0; r < TVR; r++) {
                    float gx = sh[r] - u_[r];
                    float gy = (r < TVR - 1) ? u_[r + 1] - u_[r] : 0.f;
                    float px = fmaf(0.25f, gx, px_[r]);
                    float py = fmaf(0.25f, gy, py_[r]);
                    float n2 = fmaf(px, px, fmaf(py, py, 1e-8f));
                    float inv = fminf(fast_rsq(n2), 1.f);
                    px_[r] = px * inv;
                    py_[r] = py * inv;
                }
            }
            float shf[TIR];
#pragma unroll
            for (int r = HALO; r < TVR - HALO; r++) shf[r - HALO] = __shfl_up(px_[r], 1);
#pragma unroll
            for (int r = HALO; r < TVR - HALO; r++) {
                float divx = px_[r] - shf[r - HALO];
                float divy = py_[r] - py_[r - 1];
                uf[r - HALO] = z_[r] - LAM_TV * (divx + divy);
            }
        } else {
#pragma unroll
            for (int r = 0; r < TVR; r++) {
                int gi = gi0 + r;
                float v = 0.f;
                if (colin && ((unsigned)gi < (unsigned)WID)) v = g[gi * WID + gj];
                z_[r] = v; px_[r] = 0.f; py_[r] = 0.f;
            }
            const bool gj_le0 = (gj <= 0);
            const bool gj_hi  = (gj >= WID - 1);
#pragma clang loop unroll(disable)
            for (int it = 0; it < 5; it++) {
                float u_[TVR], sh[TVR];
#pragma unroll
                for (int r = 0; r < TVR; r++) sh[r] = __shfl_up(px_[r], 1);
#pragma unroll
                for (int r = 0; r < TVR; r++) {
                    int gi = gi0 + r;
                    float divx = gj_le0 ? px_[r] : (gj_hi ? -sh[r] : px_[r] - sh[r]);
                    float pym = (r > 0) ? py_[r - 1] : py_[0];
                    float divy = (gi <= 0) ? py_[r]
                               : ((gi >= WID - 1) ? -pym : py_[r] - pym);
                    u_[r] = z_[r] - LAM_TV * (divx + divy);
                }
#pragma unroll
                for (int r = 0; r < TVR; r++) sh[r] = __shfl_down(u_[r], 1);
#pragma unroll
                for (int r = 0; r < TVR; r++) {
                    int gi = gi0 + r;
                    float ub = (r < TVR - 1) ? u_[r + 1] : u_[r];
                    float gx = (gj < WID - 1) ? sh[r] - u_[r] : 0.f;
                    float gy = (gi < WID - 1 && r < TVR - 1) ? ub - u_[r] : 0.f;
                    float px = fmaf(0.25f, gx, px_[r]);
                    float py = fmaf(0.25f, gy, py_[r]);
                    float n2 = fmaf(px, px, fmaf(py, py, 1e-8f));
                    float inv = fminf(fast_rsq(n2), 1.f);
                    px_[r] = px * inv;
                    py_[r] = py * inv;
                }
            }
            float shf[TIR];
#pragma unroll
            for (int r = HALO; r < TVR - HALO; r++) shf[r - HALO] = __shfl_up(px_[r], 1);
#pragma unroll
            for (int r = HALO; r < TVR - HALO; r++) {
                int gi = gi0 + r;
                float pxm = shf[r - HALO];
                float divx = gj_le0 ? px_[r] : (gj_hi ? -pxm : px_[r] - pxm);
                float divy = (gi <= 0) ? py_[r]
                           : ((gi >= WID - 1) ? -py_[r - 1] : py_[r] - py_[r - 1]);
                uf[r - HALO] = z_[r] - LAM_TV * (divx + divy);
            }
        }
    }

    float xn[TIR];
    haar3(uf, lane, xn);

    const bool wcol = (lane >= 8) && (lane < 56) && ((unsigned)gj < (unsigned)WID);
    float* px = x + (size_t)sl * HWc;
    const int gi_int0 = trow * TIR;
#pragma unroll
    for (int i = 0; i < TIR; i++) {
        int off = (gi_int0 + i) * WID + gj;
        if (wcol) px[off] = xn[i];
    }
}

// ---- FUSED: TV(it) strip + FISTA + rowF(it+1) from LDS ---------------------
// Block = 512 thd (8 waves) owns one 8-row full-width strip of one image:
// phase A: load zs strip rows [gi0-4, gi0+12) x 320 x 2comp into LDS;
// phase B: 14 TV tile jobs (2 comp x 7 tcol), FISTA -> x,z global + z_new LDS;
// phase C: 8 complex row-FFTs (forward) of z_new -> kout (t1).
__global__ __launch_bounds__(512) void tv_rowf(const float* __restrict__ zs,
                                               float* __restrict__ x,
                                               float* __restrict__ z,
                                               float* __restrict__ kout,
                                               float beta,
                                               const float* __restrict__ twb) {
    __shared__ float zst[2][TVR][SPAD];    // 2*16*321*4 = 41.1 KB
    __shared__ float znw[2][TIR][SPAD];    // 2*8*321*4  = 20.5 KB
    const int tid  = threadIdx.x;
    const int lane = tid & 63;
    const int wv   = __builtin_amdgcn_readfirstlane(tid >> 6);   // 0..7
    const int img  = blockIdx.x / TROWS;
    const int trow = blockIdx.x - img * TROWS;
    const int gi0  = trow * TIR - HALO;
    const size_t sbase = (size_t)img * 2 * HWc;

    // --- phase A: strip load (zero-fill OOB rows) ---
    constexpr int F4 = WID / 4;                   // 80 float4 per row
    constexpr int NA = 2 * TVR * F4;              // 2560 items
    for (int i = tid; i < NA; i += 512) {
        int comp = i / (TVR * F4);
        int rem  = i - comp * (TVR * F4);
        int r    = rem / F4;
        int cg   = (rem - r * F4) * 4;
        int gi   = gi0 + r;
        float4 v = make_float4(0.f, 0.f, 0.f, 0.f);
        if ((unsigned)gi < (unsigned)WID)
            v = *(const float4*)(zs + sbase + (size_t)comp * HWc + gi * WID + cg);
        float* t = &zst[comp][r][cg];
        t[0] = v.x; t[1] = v.y; t[2] = v.z; t[3] = v.w;
    }
    __syncthreads();

    // --- phase B: TV tiles + wavelet + FISTA ---
#pragma clang loop unroll(disable)
    for (int round = 0; round < 2; round++) {
        int j = wv + 8 * round;
        if (j < 14) {
            int comp = j / TCOLS;          // 0..1
            int tcol = j - comp * TCOLS;   // 0..6
            int gj = tcol * TIC - 8 + lane;
            const bool edge = (trow == 0) || (trow == TROWS - 1) ||
                              (tcol == 0) || (tcol == TCOLS - 1);
            float uf[TIR];
            if (!edge) tv_core_lds<false>(zst[comp], gi0, gj, uf);
            else       tv_core_lds<true >(zst[comp], gi0, gj, uf);

            float xn[TIR];
            haar3(uf, lane, xn);

            const bool wcol = (lane >= 8) && (lane < 56) &&
                              ((unsigned)gj < (unsigned)WID);
            const int sl = img * 2 + comp;
            float* px = x + (size_t)sl * HWc;
            float* pz = z + (size_t)sl * HWc;
            const int gi_int0 = trow * TIR;
#pragma unroll
            for (int i = 0; i < TIR; i++) {
                int off = (gi_int0 + i) * WID + gj;
                float xo = wcol ? px[off] : 0.f;
                float zn = xn[i] + beta * (xn[i] - xo);
                if (wcol) {
                    px[off] = xn[i];
                    pz[off] = zn;
                    znw[comp][i][gj] = zn;
                }
            }
        }
    }
    __syncthreads();

    // --- phase C: forward row FFT of z_new rows (one complex row per wave) --
    {
        Tw tw = load_tw(twb, lane);               // forward table
        const int k1 = (int)(__brev((unsigned)lane) >> 26);
        const float sgn_in = (lane & 1) ? -1.f : 1.f;
        float vr[5], vi[5];
#pragma unroll
        for (int m = 0; m < 5; m++) {
            int n = lane + 64 * m;
            vr[m] = sgn_in * znw[0][wv][n];
            vi[m] = sgn_in * znw[1][wv][n];
        }
        float Cr[5], Ci[5];
        fft320_core<-1>(vr, vi, Cr, Ci, tw, lane);
        const int gr = trow * TIR + wv;
        float* qre = kout + sbase + (size_t)gr * WID;
        float* qim = qre + HWc;
        const float scale = 0.05590169943749474f;  // 1/sqrt(320)
#pragma unroll
        for (int k = 0; k < 5; k++) {
            int ko = 5 * k1 + k;
            float s2 = (ko & 1) ? -scale : scale;
            qre[ko] = s2 * Cr[k];
            qim[ko] = s2 * Ci[k];
        }
    }
}

// ---------------- host orchestration ----------------
extern "C" void kernel_launch(void* const* d_in, const int* in_sizes, int n_in,
                              void* d_out, int out_size, void* d_ws, size_t ws_size,
                              hipStream_t stream) {
    const float* y    = (const float*)d_in[0];
    const float* mask = (const float*)d_in[1];
    float* x = (float*)d_out;

    float* ws = (float*)d_ws;
    float* z  = ws;                       // NTOT
    float* t1 = ws + (size_t)NTOT;        // NTOT (k-space / rowF output)
    float* t2 = ws + 2 * (size_t)NTOT;    // NTOT (col output)
    float* t3 = ws + 3 * (size_t)NTOT;    // NTOT (zs = z - g)
    float* tw = ws + 4 * (size_t)NTOT;    // twiddle tables
    float* twF = tw;                      // forward (SGN=-1)
    float* twI = tw + 14 * 64;            // inverse (SGN=+1)

    const int ROW_BLKS = (NIMG * 320) / 4;      // 1280
    const int COL_BLKS = NIMG * (WID / CB);     // 640
    const int FUS_BLKS = NIMG * TROWS;          // 640 strips
    const int TVL_BLKS = (NSL * TPS) / 4;       // 2240 (last iter)

    build_tw<<<1, 64, 0, stream>>>(tw);

    // x0 = ifft2c(y): col-inverse then row-inverse (dual store -> x and z)
    fft_col<0><<<COL_BLKS, 512, 0, stream>>>(y, t1, nullptr, nullptr, twF);
    fft_row<1, 3><<<ROW_BLKS, 256, 0, stream>>>(t1, x, nullptr, z, twI);
    // prologue rowF for it=0
    fft_row<-1, 0><<<ROW_BLKS, 256, 0, stream>>>(z, t1, nullptr, nullptr, twF);

    float t = 1.f;
    for (int it = 0; it < 15; it++) {
        fft_col<1><<<COL_BLKS, 512, 0, stream>>>(t1, t2, y, mask, twF);
        fft_row<1, 2><<<ROW_BLKS, 256, 0, stream>>>(t2, t3, z, nullptr, twI);

        float tn   = (1.f + sqrtf(1.f + 4.f * t * t)) * 0.5f;
        float beta = (t - 1.f) / tn;
        t = tn;
        if (it < 14)
            tv_rowf<<<FUS_BLKS, 512, 0, stream>>>(t3, x, z, t1, beta, twF);
        else
            tv_wav_last<<<TVL_BLKS, 256, 0, stream>>>(t3, x);
    }
    (void)in_sizes; (void)n_in; (void)out_size; (void)ws_size;
}